// Round 2
// baseline (871.874 us; speedup 1.0000x reference)
//
#include <hip/hip_runtime.h>

typedef unsigned short u16;
typedef unsigned int u32;
typedef __bf16 bf16x8 __attribute__((ext_vector_type(8)));
typedef float f32x4 __attribute__((ext_vector_type(4)));

#define TT 6
#define NTOK (6*40*72)      // 17280 tokens
#define KTOT 373            // keys per frame: 45 win + 148 rolled + 180 pooled
#define SCALE 0.08838834764831845f   // 1/sqrt(128)

__device__ __forceinline__ float bf2f(u16 u){ u32 x = ((u32)u) << 16; return __builtin_bit_cast(float, x); }
__device__ __forceinline__ u16 f2bf(float f){ u32 x = __builtin_bit_cast(u32, f); x += 0x7fff + ((x >> 16) & 1); return (u16)(x >> 16); }

// ---------------- float32 -> bf16 conversion (x), 4 elems/thread ----------------
__global__ __launch_bounds__(256) void convert_x(const float* __restrict__ src, u16* __restrict__ dst, int n4)
{
  int i = blockIdx.x * 256 + threadIdx.x;
  if (i >= n4) return;
  float4 v = *(const float4*)(src + (size_t)i * 4);
  u16 o[4] = {f2bf(v.x), f2bf(v.y), f2bf(v.z), f2bf(v.w)};
  *(uint2*)(dst + (size_t)i * 4) = *(const uint2*)o;
}

// ---------------- weight transpose: out[m][n][k] = bf16(W_m[k][n]) ----------------
__global__ __launch_bounds__(256) void transpose_w(
    const float* __restrict__ w0, const float* __restrict__ w1,
    const float* __restrict__ w2, const float* __restrict__ w3, u16* __restrict__ out)
{
  int m = blockIdx.y;
  const float* src = m == 0 ? w0 : (m == 1 ? w1 : (m == 2 ? w2 : w3));
  int idx = blockIdx.x * 256 + threadIdx.x;   // = n*512 + k
  int n = idx >> 9, k = idx & 511;
  out[m * 262144 + idx] = f2bf(src[k * 512 + n]);
}

// ---------------- GEMM: C[M][512] = A[M][512] @ W + bias, bf16 in, fp32 acc.
// Wt pre-transposed bf16 (Bt[n][k]); bias fp32; output bf16 (c*) or fp32 (cf).
__global__ __launch_bounds__(256) void gemm_bias(
    const u16* __restrict__ A, const u16* __restrict__ wt,
    const float* __restrict__ b0, const float* __restrict__ b1, const float* __restrict__ b2,
    u16* __restrict__ c0, u16* __restrict__ c1, u16* __restrict__ c2, float* __restrict__ cf,
    int wo0, int wo1, int wo2, int M)
{
  __shared__ __align__(16) u16 sA[128][40];   // pad 32->40: 2-way bank alias (free)
  __shared__ __align__(16) u16 sB[128][40];
  int z = blockIdx.z;
  const u16* Bt = wt + (size_t)(z == 0 ? wo0 : (z == 1 ? wo1 : wo2)) * 262144;
  const float* bias = z == 0 ? b0 : (z == 1 ? b1 : b2);
  u16* Cout = z == 0 ? c0 : (z == 1 ? c1 : c2);
  int mbase = blockIdx.x * 128, nbase = blockIdx.y * 128;
  int tid = threadIdx.x, lane = tid & 63, wave = tid >> 6;
  int wm = (wave >> 1) * 64, wn = (wave & 1) * 64;
  int quad = lane >> 4, tr = lane & 15;
  f32x4 acc[4][4];
#pragma unroll
  for (int i = 0; i < 4; i++)
#pragma unroll
    for (int j = 0; j < 4; j++){ acc[i][j][0]=0.f; acc[i][j][1]=0.f; acc[i][j][2]=0.f; acc[i][j][3]=0.f; }

  for (int k0 = 0; k0 < 512; k0 += 32){
    if (k0) __syncthreads();
#pragma unroll
    for (int r = 0; r < 2; r++){
      int u = tid + 256 * r;
      int row = u >> 2, kg = (u & 3) * 8;
      int grow = mbase + row;
      uint4 va = make_uint4(0,0,0,0);
      if (grow < M) va = *(const uint4*)(A + (size_t)grow * 512 + k0 + kg);
      *(uint4*)(&sA[row][kg]) = va;
      uint4 vb = *(const uint4*)(Bt + (size_t)(nbase + row) * 512 + k0 + kg);
      *(uint4*)(&sB[row][kg]) = vb;
    }
    __syncthreads();
    bf16x8 a[4], b[4];
#pragma unroll
    for (int i = 0; i < 4; i++) a[i] = *(const bf16x8*)(&sA[wm + i*16 + tr][quad * 8]);
#pragma unroll
    for (int j = 0; j < 4; j++) b[j] = *(const bf16x8*)(&sB[wn + j*16 + tr][quad * 8]);
#pragma unroll
    for (int i = 0; i < 4; i++)
#pragma unroll
      for (int j = 0; j < 4; j++)
        acc[i][j] = __builtin_amdgcn_mfma_f32_16x16x32_bf16(a[i], b[j], acc[i][j], 0, 0, 0);
  }

#pragma unroll
  for (int j = 0; j < 4; j++){
    int col = nbase + wn + j*16 + tr;
    float bv = bias[col];
#pragma unroll
    for (int i = 0; i < 4; i++)
#pragma unroll
      for (int r2 = 0; r2 < 4; r2++){
        int row = mbase + wm + i*16 + quad*4 + r2;
        if (row < M){
          float val = acc[i][j][r2] + bv;
          if (cf) cf[(size_t)row * 512 + col] = val;
          else    Cout[(size_t)row * 512 + col] = f2bf(val);
        }
      }
  }
}

// ---------------- depthwise 4x4/4 pool conv: px[1080][512] bf16 ----------------
__global__ __launch_bounds__(256) void pool_conv(
    const float* __restrict__ x, const float* __restrict__ pw,
    const float* __restrict__ pb, u16* __restrict__ px)
{
  int idx = blockIdx.x * 256 + threadIdx.x;   // 6*10*18*512 = 552960
  int c = idx & 511, n = idx >> 9;
  int f = n / 180, rp = n % 180, ph = rp / 18, pwc = rp % 18;
  float acc = pb[c];
#pragma unroll
  for (int i = 0; i < 4; i++)
#pragma unroll
    for (int j = 0; j < 4; j++){
      int hh = ph*4 + i, ww = pwc*4 + j;
      acc += x[((size_t)((f*40 + hh)*72 + ww)) * 512 + c] * pw[(i*4 + j)*512 + c];
    }
  px[idx] = f2bf(acc);
}

// ---------------- window mask + VALID_IND compaction table ----------------
__global__ void prep(const float* __restrict__ masks, int* __restrict__ wmask, int* __restrict__ vi)
{
  int tid = threadIdx.x;
  if (tid < 64){
    int wi = tid >> 3, wj = tid & 7;
    int flag = 0;
    for (int f = 0; f < 6; f++)
      for (int p = 0; p < 45; p++){
        int hh = wi*5 + p/9, ww = wj*9 + p%9;
        if (masks[(f*40 + hh)*72 + ww] > 0.f) flag = 1;
      }
    wmask[tid] = flag;
  } else if (tid == 64){
    int cnt = 0;
    for (int e = 0; e < 180; e++){
      int s = e / 45, pos = e % 45, pr = pos / 9, pc = pos % 9;
      bool inval = (s == 0 && pr < 2 && pc < 4) || (s == 1 && pr < 2 && pc >= 5) ||
                   (s == 2 && pr >= 3 && pc < 4) || (s == 3 && pr >= 3 && pc >= 5);
      if (!inval) vi[cnt++] = e;
    }
  }
}

// key slot -> source row pointer (token buffers or pooled buffers)
__device__ __forceinline__ const u16* key_src(int jg, int masked, int qf, int wi, int wj, int head,
    const u16* __restrict__ tokbuf, const u16* __restrict__ poolbuf, const int* sVI)
{
  int f, slot;
  if (masked){ f = jg / KTOT; slot = jg - f * KTOT; } else { f = qf; slot = jg; }
  if (slot < 45){
    int hh = wi*5 + slot/9, ww = wj*9 + slot%9;
    return tokbuf + ((size_t)((f*40 + hh)*72 + ww)) * 512 + head * 128;
  } else if (slot < 193){
    int e = sVI[slot - 45];
    int s2 = e / 45, pos = e - s2*45, pr = pos / 9, pc = pos - pr*9;
    // roll(k, (-a,-b)) => rolled[h][w] = k[(h+a)%H][(w+b)%W]; shifts (∓3, ∓5)
    int hh = wi*5 + pr + ((s2 < 2) ? 3 : -3);
    int ww = wj*9 + pc + ((s2 & 1) ? -5 : 5);
    if (hh < 0) hh += 40; else if (hh >= 40) hh -= 40;
    if (ww < 0) ww += 72; else if (ww >= 72) ww -= 72;
    return tokbuf + ((size_t)((f*40 + hh)*72 + ww)) * 512 + head * 128;
  } else {
    return poolbuf + ((size_t)(f*180 + (slot - 193))) * 512 + head * 128;
  }
}

// ---------------- attention: block = (window, head, q-frame) ----------------
__global__ __launch_bounds__(256) void attn(
    const u16* __restrict__ qb, const u16* __restrict__ kb, const u16* __restrict__ vb,
    const u16* __restrict__ pkb, const u16* __restrict__ pvb,
    const int* __restrict__ wmaskp, const int* __restrict__ vip,
    u16* __restrict__ yb)
{
  __shared__ __align__(16) u16 sQ[48][136];    // 45 q rows (3 pad, zeroed), hd=128 (+8 pad)
  __shared__ __align__(16) u16 sK[64][136];    // key chunk
  __shared__ __align__(16) u16 sVt[128][72];   // V^T: [hd][key] (+8 pad)
  __shared__ __align__(16) u16 sP[48][72];     // exp(S) in bf16
  __shared__ float sDen[48];
  __shared__ int sVI[148];

  int win = blockIdx.x, head = blockIdx.y, qf = blockIdx.z;
  int wi = win >> 3, wj = win & 7;
  int tid = threadIdx.x, lane = tid & 63, wave = tid >> 6;
  int quad = lane >> 4, tr = lane & 15;

  if (tid < 148) sVI[tid] = vip[tid];
  if (tid < 48) sDen[tid] = 0.f;

#pragma unroll
  for (int r = 0; r < 3; r++){              // 48 rows x 16 groups of 8
    int u = tid + 256 * r;
    int row = u >> 4, dg = u & 15;
    uint4 val = make_uint4(0,0,0,0);
    if (row < 45){
      int hh = wi*5 + row/9, ww = wj*9 + row%9;
      val = *(const uint4*)(qb + ((size_t)((qf*40 + hh)*72 + ww)) * 512 + head*128 + dg*8);
    }
    *(uint4*)(&sQ[row][dg * 8]) = val;
  }

  int masked = wmaskp[win];
  int nkeys = masked ? TT * KTOT : 45;      // 2238 dense / 45 local
  int nchunk = (nkeys + 63) >> 6;

  f32x4 acc[3][2];
#pragma unroll
  for (int a = 0; a < 3; a++)
#pragma unroll
    for (int b = 0; b < 2; b++){ acc[a][b][0]=0.f; acc[a][b][1]=0.f; acc[a][b][2]=0.f; acc[a][b][3]=0.f; }

  __syncthreads();

  for (int ch = 0; ch < nchunk; ch++){
    // ---- stage K chunk (coalesced: 16 lanes per key row) ----
#pragma unroll
    for (int r = 0; r < 4; r++){
      int u = tid + 256 * r;
      int key = u >> 4, dg = u & 15;
      int jg = ch * 64 + key;
      uint4 val = make_uint4(0,0,0,0);
      if (jg < nkeys){
        const u16* src = key_src(jg, masked, qf, wi, wj, head, kb, pkb, sVI);
        val = *(const uint4*)(src + dg * 8);
      }
      *(uint4*)(&sK[key][dg * 8]) = val;
    }
    // ---- stage V chunk transposed ----
#pragma unroll
    for (int r = 0; r < 4; r++){
      int u = tid + 256 * r;
      int key = u & 63, dg = u >> 6;
      int jg = ch * 64 + key;
      uint4 val = make_uint4(0,0,0,0);
      if (jg < nkeys){
        const u16* src = key_src(jg, masked, qf, wi, wj, head, vb, pvb, sVI);
        val = *(const uint4*)(src + dg * 8);
      }
      u32 vv[4] = {val.x, val.y, val.z, val.w};
#pragma unroll
      for (int q2 = 0; q2 < 4; q2++){
        sVt[dg*8 + q2*2][key]     = (u16)(vv[q2] & 0xffff);
        sVt[dg*8 + q2*2 + 1][key] = (u16)(vv[q2] >> 16);
      }
    }
    __syncthreads();

    // ---- QK^T: wave owns 16-key n-tile [16*wave, 16*wave+16) ----
#pragma unroll
    for (int mt = 0; mt < 3; mt++){
      f32x4 sacc = {0.f, 0.f, 0.f, 0.f};
#pragma unroll
      for (int kt = 0; kt < 4; kt++){
        bf16x8 a = *(const bf16x8*)(&sQ[mt*16 + tr][kt*32 + quad*8]);
        bf16x8 b = *(const bf16x8*)(&sK[wave*16 + tr][kt*32 + quad*8]);
        sacc = __builtin_amdgcn_mfma_f32_16x16x32_bf16(a, b, sacc, 0, 0, 0);
      }
      int colg = ch * 64 + wave * 16 + tr;
      float pr4[4];
#pragma unroll
      for (int r2 = 0; r2 < 4; r2++){
        // no max-subtraction: logits are small (|s|<~1.5), softmax is shift-invariant
        float p = (colg < nkeys) ? __expf(sacc[r2] * SCALE) : 0.f;
        u16 pb2 = f2bf(p);
        sP[mt*16 + quad*4 + r2][wave*16 + tr] = pb2;
        pr4[r2] = bf2f(pb2);   // den from ROUNDED p: num/den rounding cancels
      }
#pragma unroll
      for (int r2 = 0; r2 < 4; r2++){
        float ps = pr4[r2];
        ps += __shfl_xor(ps, 1, 64);
        ps += __shfl_xor(ps, 2, 64);
        ps += __shfl_xor(ps, 4, 64);
        ps += __shfl_xor(ps, 8, 64);
        if (tr == 0) atomicAdd(&sDen[mt*16 + quad*4 + r2], ps);
      }
    }
    __syncthreads();

    // ---- PV: wave owns hd columns [32*wave, 32*wave+32) ----
#pragma unroll
    for (int mt = 0; mt < 3; mt++)
#pragma unroll
      for (int nt = 0; nt < 2; nt++)
#pragma unroll
        for (int kt = 0; kt < 2; kt++){
          bf16x8 a = *(const bf16x8*)(&sP[mt*16 + tr][kt*32 + quad*8]);
          bf16x8 b = *(const bf16x8*)(&sVt[wave*32 + nt*16 + tr][kt*32 + quad*8]);
          acc[mt][nt] = __builtin_amdgcn_mfma_f32_16x16x32_bf16(a, b, acc[mt][nt], 0, 0, 0);
        }
    __syncthreads();
  }

  // ---- epilogue: divide by den, scatter to y in (t,h,w,c) layout ----
#pragma unroll
  for (int mt = 0; mt < 3; mt++)
#pragma unroll
    for (int r2 = 0; r2 < 4; r2++){
      int row = mt*16 + quad*4 + r2;
      if (row < 45){
        float dinv = 1.0f / sDen[row];
        int hh = wi*5 + row/9, ww = wj*9 + row%9;
        size_t base = ((size_t)((qf*40 + hh)*72 + ww)) * 512 + head * 128;
#pragma unroll
        for (int nt = 0; nt < 2; nt++){
          int col = wave*32 + nt*16 + tr;
          yb[base + col] = f2bf(acc[mt][nt][r2] * dinv);
        }
      }
    }
}

extern "C" void kernel_launch(void* const* d_in, const int* in_sizes, int n_in,
                              void* d_out, int out_size, void* d_ws, size_t ws_size,
                              hipStream_t stream)
{
  const float* x     = (const float*)d_in[0];
  const float* masks = (const float*)d_in[1];
  const float* Wq = (const float*)d_in[2];  const float* bq = (const float*)d_in[3];
  const float* Wk = (const float*)d_in[4];  const float* bk = (const float*)d_in[5];
  const float* Wv = (const float*)d_in[6];  const float* bv = (const float*)d_in[7];
  const float* Wp = (const float*)d_in[8];  const float* bp = (const float*)d_in[9];
  const float* pw = (const float*)d_in[10]; const float* pb = (const float*)d_in[11];
  float* out = (float*)d_out;

  char* ws = (char*)d_ws;
  size_t off = 0;
  auto alloc = [&](size_t bytes) -> char* {
    char* p = ws + off; off += (bytes + 255) & ~(size_t)255; return p;
  };
  u16* wt    = (u16*)alloc((size_t)4 * 512 * 512 * 2);   // Wq^T,Wk^T,Wv^T,Wp^T (bf16)
  u16* xbf   = (u16*)alloc((size_t)NTOK * 512 * 2);
  u16* qbuf  = (u16*)alloc((size_t)NTOK * 512 * 2);
  u16* kbuf  = (u16*)alloc((size_t)NTOK * 512 * 2);
  u16* vbuf  = (u16*)alloc((size_t)NTOK * 512 * 2);
  u16* pxbuf = (u16*)alloc((size_t)1080 * 512 * 2);
  u16* pkbuf = (u16*)alloc((size_t)1080 * 512 * 2);
  u16* pvbuf = (u16*)alloc((size_t)1080 * 512 * 2);
  u16* ybuf  = (u16*)alloc((size_t)NTOK * 512 * 2);
  int* wmaskb = (int*)alloc(64 * 4);
  int* vib    = (int*)alloc(148 * 4);

  convert_x<<<dim3((NTOK*512/4 + 255)/256), 256, 0, stream>>>(x, xbf, NTOK*512/4);
  transpose_w<<<dim3(1024, 4), 256, 0, stream>>>(Wq, Wk, Wv, Wp, wt);
  gemm_bias<<<dim3(135, 4, 3), 256, 0, stream>>>(xbf, wt, bq, bk, bv, qbuf, kbuf, vbuf, nullptr, 0, 1, 2, NTOK);
  pool_conv<<<dim3(2160), 256, 0, stream>>>(x, pw, pb, pxbuf);
  gemm_bias<<<dim3(9, 4, 2), 256, 0, stream>>>(pxbuf, wt, bk, bv, bv, pkbuf, pvbuf, pvbuf, nullptr, 1, 2, 2, 1080);
  prep<<<dim3(1), 128, 0, stream>>>(masks, wmaskb, vib);
  attn<<<dim3(64, 4, 6), 256, 0, stream>>>(qbuf, kbuf, vbuf, pkbuf, pvbuf, wmaskb, vib, ybuf);
  gemm_bias<<<dim3(135, 4, 1), 256, 0, stream>>>(ybuf, wt, bp, bp, bp, nullptr, nullptr, nullptr, out, 3, 3, 3, NTOK);
}

// Round 3
// 419.716 us; speedup vs baseline: 2.0773x; 2.0773x over previous
//
#include <hip/hip_runtime.h>

typedef unsigned short u16;
typedef unsigned int u32;
typedef __bf16 bf16x8 __attribute__((ext_vector_type(8)));
typedef float f32x4 __attribute__((ext_vector_type(4)));

#define TT 6
#define NTOK (6*40*72)      // 17280 tokens
#define KTOT 373            // keys per frame: 45 win + 148 rolled + 180 pooled
#define NKEYS (TT*KTOT)     // 2238 dense keys
#define NCH 70              // ceil(2238/32)
#define SCALE 0.08838834764831845f   // 1/sqrt(128)

__device__ __forceinline__ float bf2f(u16 u){ u32 x = ((u32)u) << 16; return __builtin_bit_cast(float, x); }
__device__ __forceinline__ u16 f2bf(float f){ u32 x = __builtin_bit_cast(u32, f); x += 0x7fff + ((x >> 16) & 1); return (u16)(x >> 16); }

// ---------------- float32 -> bf16 conversion (x), 4 elems/thread ----------------
__global__ __launch_bounds__(256) void convert_x(const float* __restrict__ src, u16* __restrict__ dst, int n4)
{
  int i = blockIdx.x * 256 + threadIdx.x;
  if (i >= n4) return;
  float4 v = *(const float4*)(src + (size_t)i * 4);
  u16 o[4] = {f2bf(v.x), f2bf(v.y), f2bf(v.z), f2bf(v.w)};
  *(uint2*)(dst + (size_t)i * 4) = *(const uint2*)o;
}

// ---------------- weight transpose: out[m][n][k] = bf16(W_m[k][n]) ----------------
__global__ __launch_bounds__(256) void transpose_w(
    const float* __restrict__ w0, const float* __restrict__ w1,
    const float* __restrict__ w2, const float* __restrict__ w3, u16* __restrict__ out)
{
  int m = blockIdx.y;
  const float* src = m == 0 ? w0 : (m == 1 ? w1 : (m == 2 ? w2 : w3));
  int idx = blockIdx.x * 256 + threadIdx.x;   // = n*512 + k
  int n = idx >> 9, k = idx & 511;
  out[m * 262144 + idx] = f2bf(src[k * 512 + n]);
}

// ---------------- GEMM: C[M][512] = A[M][512] @ W + bias ----------------
__global__ __launch_bounds__(256) void gemm_bias(
    const u16* __restrict__ A, const u16* __restrict__ wt,
    const float* __restrict__ b0, const float* __restrict__ b1, const float* __restrict__ b2,
    u16* __restrict__ c0, u16* __restrict__ c1, u16* __restrict__ c2, float* __restrict__ cf,
    int wo0, int wo1, int wo2, int M)
{
  __shared__ __align__(16) u16 sA[128][40];
  __shared__ __align__(16) u16 sB[128][40];
  int z = blockIdx.z;
  const u16* Bt = wt + (size_t)(z == 0 ? wo0 : (z == 1 ? wo1 : wo2)) * 262144;
  const float* bias = z == 0 ? b0 : (z == 1 ? b1 : b2);
  u16* Cout = z == 0 ? c0 : (z == 1 ? c1 : c2);
  int mbase = blockIdx.x * 128, nbase = blockIdx.y * 128;
  int tid = threadIdx.x, lane = tid & 63, wave = tid >> 6;
  int wm = (wave >> 1) * 64, wn = (wave & 1) * 64;
  int quad = lane >> 4, tr = lane & 15;
  f32x4 acc[4][4];
#pragma unroll
  for (int i = 0; i < 4; i++)
#pragma unroll
    for (int j = 0; j < 4; j++){ acc[i][j][0]=0.f; acc[i][j][1]=0.f; acc[i][j][2]=0.f; acc[i][j][3]=0.f; }

  for (int k0 = 0; k0 < 512; k0 += 32){
    if (k0) __syncthreads();
#pragma unroll
    for (int r = 0; r < 2; r++){
      int u = tid + 256 * r;
      int row = u >> 2, kg = (u & 3) * 8;
      int grow = mbase + row;
      uint4 va = make_uint4(0,0,0,0);
      if (grow < M) va = *(const uint4*)(A + (size_t)grow * 512 + k0 + kg);
      *(uint4*)(&sA[row][kg]) = va;
      uint4 vb = *(const uint4*)(Bt + (size_t)(nbase + row) * 512 + k0 + kg);
      *(uint4*)(&sB[row][kg]) = vb;
    }
    __syncthreads();
    bf16x8 a[4], b[4];
#pragma unroll
    for (int i = 0; i < 4; i++) a[i] = *(const bf16x8*)(&sA[wm + i*16 + tr][quad * 8]);
#pragma unroll
    for (int j = 0; j < 4; j++) b[j] = *(const bf16x8*)(&sB[wn + j*16 + tr][quad * 8]);
#pragma unroll
    for (int i = 0; i < 4; i++)
#pragma unroll
      for (int j = 0; j < 4; j++)
        acc[i][j] = __builtin_amdgcn_mfma_f32_16x16x32_bf16(a[i], b[j], acc[i][j], 0, 0, 0);
  }

#pragma unroll
  for (int j = 0; j < 4; j++){
    int col = nbase + wn + j*16 + tr;
    float bv = bias[col];
#pragma unroll
    for (int i = 0; i < 4; i++)
#pragma unroll
      for (int r2 = 0; r2 < 4; r2++){
        int row = mbase + wm + i*16 + quad*4 + r2;
        if (row < M){
          float val = acc[i][j][r2] + bv;
          if (cf) cf[(size_t)row * 512 + col] = val;
          else    Cout[(size_t)row * 512 + col] = f2bf(val);
        }
      }
  }
}

// ---------------- depthwise 4x4/4 pool conv: px[1080][512] bf16 ----------------
__global__ __launch_bounds__(256) void pool_conv(
    const float* __restrict__ x, const float* __restrict__ pw,
    const float* __restrict__ pb, u16* __restrict__ px)
{
  int idx = blockIdx.x * 256 + threadIdx.x;
  int c = idx & 511, n = idx >> 9;
  int f = n / 180, rp = n % 180, ph = rp / 18, pwc = rp % 18;
  float acc = pb[c];
#pragma unroll
  for (int i = 0; i < 4; i++)
#pragma unroll
    for (int j = 0; j < 4; j++){
      int hh = ph*4 + i, ww = pwc*4 + j;
      acc += x[((size_t)((f*40 + hh)*72 + ww)) * 512 + c] * pw[(i*4 + j)*512 + c];
    }
  px[idx] = f2bf(acc);
}

// ---------------- window mask + VALID_IND compaction table ----------------
__global__ void prep(const float* __restrict__ masks, int* __restrict__ wmask, int* __restrict__ vi)
{
  int tid = threadIdx.x;
  if (tid < 64){
    int wi = tid >> 3, wj = tid & 7;
    int flag = 0;
    for (int f = 0; f < 6; f++)
      for (int p = 0; p < 45; p++){
        int hh = wi*5 + p/9, ww = wj*9 + p%9;
        if (masks[(f*40 + hh)*72 + ww] > 0.f) flag = 1;
      }
    wmask[tid] = flag;
  } else if (tid == 64){
    int cnt = 0;
    for (int e = 0; e < 180; e++){
      int s = e / 45, pos = e % 45, pr = pos / 9, pc = pos % 9;
      bool inval = (s == 0 && pr < 2 && pc < 4) || (s == 1 && pr < 2 && pc >= 5) ||
                   (s == 2 && pr >= 3 && pc < 4) || (s == 3 && pr >= 3 && pc >= 5);
      if (!inval) vi[cnt++] = e;
    }
  }
}

// ================= DENSE attention: block = (window, head), all 6 frames =================
// M = 288 rows (6 frames x 48, rows 45..47 per frame are zero-pad), 18 m-tiles.
// Wave w owns m-tiles {2w, 2w+1}; tiles 16,17 are split across waves (balanced 36 MFMA/wave/chunk).
__global__ __launch_bounds__(512) void attn_dense(
    const u16* __restrict__ qb, const u16* __restrict__ kb, const u16* __restrict__ vb,
    const u16* __restrict__ pkb, const u16* __restrict__ pvb,
    const int* __restrict__ wmaskp, const int* __restrict__ vip,
    u16* __restrict__ yb)
{
  __shared__ __align__(16) u16 sK[32][136];   // 32-key chunk, row stride 136 (68 dw ≡ 4 mod 32: conflict-free b128 phases)
  __shared__ __align__(16) u16 sVt[128][40];  // V^T [hd][key]
  __shared__ __align__(16) u16 sP[288][40];   // exp(S) bf16
  __shared__ int sIdx[2240];                  // key -> token row (>=0) or ~poolrow (<0)
  __shared__ int sVI[148];
  __shared__ float sDenX[32];                 // den for tiles 16,17 (cross-wave)

  int win = blockIdx.x, head = blockIdx.y;
  if (!wmaskp[win]) return;                   // local windows handled by attn_local
  int wi = win >> 3, wj = win & 7;
  int tid = threadIdx.x, lane = tid & 63, wave = tid >> 6;
  int quad = lane >> 4, tr = lane & 15;

  if (tid < 148) sVI[tid] = vip[tid];
  if (tid < 32) sDenX[tid] = 0.f;
  __syncthreads();

  // ---- build per-window gather table once (all divides happen here) ----
  for (int i = tid; i < NKEYS; i += 512){
    int f = i / KTOT, slot = i - f * KTOT;
    int idx;
    if (slot < 45){
      int hh = wi*5 + slot/9, ww = wj*9 + slot%9;
      idx = (f*40 + hh)*72 + ww;
    } else if (slot < 193){
      int e = sVI[slot - 45];
      int s2 = e / 45, pos = e - s2*45, pr = pos/9, pc = pos - pr*9;
      int hh = wi*5 + pr + ((s2 < 2) ? 3 : -3);
      int ww = wj*9 + pc + ((s2 & 1) ? -5 : 5);
      if (hh < 0) hh += 40; else if (hh >= 40) hh -= 40;
      if (ww < 0) ww += 72; else if (ww >= 72) ww -= 72;
      idx = (f*40 + hh)*72 + ww;
    } else {
      idx = ~(f*180 + (slot - 193));
    }
    sIdx[i] = idx;
  }

  // ---- Q fragments in registers (loaded once): own tiles 2w,2w+1 + shared tile 16+(w>>2) ----
  int mts[3] = {2*wave, 2*wave + 1, 16 + (wave >> 2)};
  bf16x8 qf[3][4];
#pragma unroll
  for (int im = 0; im < 3; im++){
    int row = mts[im]*16 + tr;
    int f = row / 48, r = row - f*48;
    bool vld = r < 45;
    int hh = wi*5 + r/9, ww = wj*9 + r%9;
    const u16* qp = qb + ((size_t)((f*40 + hh)*72 + ww))*512 + head*128;
#pragma unroll
    for (int kt = 0; kt < 4; kt++){
      uint4 v = make_uint4(0,0,0,0);
      if (vld) v = *(const uint4*)(qp + kt*32 + quad*8);
      qf[im][kt] = __builtin_bit_cast(bf16x8, v);
    }
  }

  f32x4 accv[2][8], accx[2];
#pragma unroll
  for (int m = 0; m < 2; m++)
#pragma unroll
    for (int nt = 0; nt < 8; nt++){ accv[m][nt][0]=0.f; accv[m][nt][1]=0.f; accv[m][nt][2]=0.f; accv[m][nt][3]=0.f; }
  accx[0][0]=0.f; accx[0][1]=0.f; accx[0][2]=0.f; accx[0][3]=0.f;
  accx[1][0]=0.f; accx[1][1]=0.f; accx[1][2]=0.f; accx[1][3]=0.f;
  float dacc[2][4], daccx[4];
#pragma unroll
  for (int m = 0; m < 2; m++)
#pragma unroll
    for (int r2 = 0; r2 < 4; r2++) dacc[m][r2] = 0.f;
#pragma unroll
  for (int r2 = 0; r2 < 4; r2++) daccx[r2] = 0.f;

  __syncthreads();   // sIdx ready

  // register prefetch of chunk ch (K: key=tid>>4, dg=tid&15; V: key=tid&31, dg=tid>>5)
  uint4 pfk, pfv;
  auto pref = [&](int ch){
    pfk = make_uint4(0,0,0,0); pfv = make_uint4(0,0,0,0);
    if (ch < NCH){
      int jg = ch*32 + (tid >> 4);
      if (jg < NKEYS){
        int idx = sIdx[jg];
        const u16* src = (idx >= 0) ? (kb + (size_t)idx*512) : (pkb + (size_t)(~idx)*512);
        pfk = *(const uint4*)(src + head*128 + (tid & 15)*8);
      }
      jg = ch*32 + (tid & 31);
      if (jg < NKEYS){
        int idx = sIdx[jg];
        const u16* src = (idx >= 0) ? (vb + (size_t)idx*512) : (pvb + (size_t)(~idx)*512);
        pfv = *(const uint4*)(src + head*128 + (tid >> 5)*8);
      }
    }
  };
  pref(0);

  for (int ch = 0; ch < NCH; ch++){
    __syncthreads();               // prev PV done; sK/sVt free
    *(uint4*)(&sK[tid >> 4][(tid & 15)*8]) = pfk;
    {
      int keyv = tid & 31, dgv = tid >> 5;
      u32 vv[4] = {pfv.x, pfv.y, pfv.z, pfv.w};
#pragma unroll
      for (int q2 = 0; q2 < 4; q2++){
        sVt[dgv*8 + q2*2][keyv]     = (u16)(vv[q2] & 0xffff);
        sVt[dgv*8 + q2*2 + 1][keyv] = (u16)(vv[q2] >> 16);
      }
    }
    __syncthreads();               // staged
    pref(ch + 1);                  // overlap next gather with compute

    // ---- QK^T + exp ----
#pragma unroll
    for (int nt = 0; nt < 2; nt++){
      bf16x8 bk[4];
#pragma unroll
      for (int kt = 0; kt < 4; kt++) bk[kt] = *(const bf16x8*)(&sK[nt*16 + tr][kt*32 + quad*8]);
      int colg = ch*32 + nt*16 + tr;
      bool vld = colg < NKEYS;
#pragma unroll
      for (int m = 0; m < 2; m++){
        f32x4 s = {0.f, 0.f, 0.f, 0.f};
#pragma unroll
        for (int kt = 0; kt < 4; kt++) s = __builtin_amdgcn_mfma_f32_16x16x32_bf16(qf[m][kt], bk[kt], s, 0, 0, 0);
        int mt = 2*wave + m;
#pragma unroll
        for (int r2 = 0; r2 < 4; r2++){
          float p = vld ? __expf(s[r2] * SCALE) : 0.f;   // no max-sub: logits small, softmax shift-invariant
          u16 pb2 = f2bf(p);
          sP[mt*16 + quad*4 + r2][nt*16 + tr] = pb2;
          dacc[m][r2] += bf2f(pb2);
        }
      }
      if (((wave & 2) == 0) && nt == (wave & 1)){   // tile 16: waves 0,1; tile 17: waves 4,5
        f32x4 s = {0.f, 0.f, 0.f, 0.f};
#pragma unroll
        for (int kt = 0; kt < 4; kt++) s = __builtin_amdgcn_mfma_f32_16x16x32_bf16(qf[2][kt], bk[kt], s, 0, 0, 0);
        int e = 16 + (wave >> 2);
#pragma unroll
        for (int r2 = 0; r2 < 4; r2++){
          float p = vld ? __expf(s[r2] * SCALE) : 0.f;
          u16 pb2 = f2bf(p);
          sP[e*16 + quad*4 + r2][nt*16 + tr] = pb2;
          daccx[r2] += bf2f(pb2);
        }
      }
    }
    __syncthreads();               // sP complete (incl. cross-wave tiles 16,17)

    // ---- PV (k = 32 keys, single k-step) ----
    {
      bf16x8 a0 = *(const bf16x8*)(&sP[(2*wave)*16 + tr][quad*8]);
      bf16x8 a1 = *(const bf16x8*)(&sP[(2*wave + 1)*16 + tr][quad*8]);
      bf16x8 ax = *(const bf16x8*)(&sP[(16 + (wave >> 2))*16 + tr][quad*8]);
#pragma unroll
      for (int nt = 0; nt < 8; nt++){
        bf16x8 bv = *(const bf16x8*)(&sVt[nt*16 + tr][quad*8]);
        accv[0][nt] = __builtin_amdgcn_mfma_f32_16x16x32_bf16(a0, bv, accv[0][nt], 0, 0, 0);
        accv[1][nt] = __builtin_amdgcn_mfma_f32_16x16x32_bf16(a1, bv, accv[1][nt], 0, 0, 0);
      }
      int he0 = (wave & 3)*2;
      bf16x8 bx0 = *(const bf16x8*)(&sVt[he0*16 + tr][quad*8]);
      bf16x8 bx1 = *(const bf16x8*)(&sVt[(he0+1)*16 + tr][quad*8]);
      accx[0] = __builtin_amdgcn_mfma_f32_16x16x32_bf16(ax, bx0, accx[0], 0, 0, 0);
      accx[1] = __builtin_amdgcn_mfma_f32_16x16x32_bf16(ax, bx1, accx[1], 0, 0, 0);
    }
  }

  // ---- cross-wave den for tiles 16,17 ----
  if ((wave & 2) == 0){
#pragma unroll
    for (int r2 = 0; r2 < 4; r2++){
      float d = daccx[r2];
      d += __shfl_xor(d, 1, 64); d += __shfl_xor(d, 2, 64);
      d += __shfl_xor(d, 4, 64); d += __shfl_xor(d, 8, 64);
      if (tr == 0) atomicAdd(&sDenX[(wave >> 2)*16 + quad*4 + r2], d);
    }
  }
  __syncthreads();

  // ---- epilogue: own tiles (den fully in registers) ----
#pragma unroll
  for (int m = 0; m < 2; m++){
#pragma unroll
    for (int r2 = 0; r2 < 4; r2++){
      float d = dacc[m][r2];
      d += __shfl_xor(d, 1, 64); d += __shfl_xor(d, 2, 64);
      d += __shfl_xor(d, 4, 64); d += __shfl_xor(d, 8, 64);
      float dinvv = 1.f / d;
      int row = (2*wave + m)*16 + quad*4 + r2;
      int f = row / 48, r = row - f*48;
      if (r < 45){
        int hh = wi*5 + r/9, ww = wj*9 + r%9;
        size_t base = ((size_t)((f*40 + hh)*72 + ww))*512 + head*128;
#pragma unroll
        for (int nt = 0; nt < 8; nt++)
          yb[base + nt*16 + tr] = f2bf(accv[m][nt][r2] * dinvv);
      }
    }
  }
  // ---- epilogue: shared tile ----
  {
    int e = 16 + (wave >> 2), he0 = (wave & 3)*2;
#pragma unroll
    for (int r2 = 0; r2 < 4; r2++){
      int row = e*16 + quad*4 + r2;
      int f = row / 48, r = row - f*48;
      if (r < 45){
        float dinvv = 1.f / sDenX[(e - 16)*16 + quad*4 + r2];
        int hh = wi*5 + r/9, ww = wj*9 + r%9;
        size_t base = ((size_t)((f*40 + hh)*72 + ww))*512 + head*128;
        yb[base + he0*16 + tr]       = f2bf(accx[0][r2] * dinvv);
        yb[base + (he0 + 1)*16 + tr] = f2bf(accx[1][r2] * dinvv);
      }
    }
  }
}

// ---------------- LOCAL (unmasked) windows: per-frame 45-key attention ----------------
__device__ __forceinline__ const u16* key_src_local(int slot, int qf, int wi, int wj, int head,
    const u16* __restrict__ tokbuf)
{
  int hh = wi*5 + slot/9, ww = wj*9 + slot%9;
  return tokbuf + ((size_t)((qf*40 + hh)*72 + ww)) * 512 + head * 128;
}

__global__ __launch_bounds__(256) void attn_local(
    const u16* __restrict__ qb, const u16* __restrict__ kb, const u16* __restrict__ vb,
    const int* __restrict__ wmaskp, u16* __restrict__ yb)
{
  __shared__ __align__(16) u16 sQ[48][136];
  __shared__ __align__(16) u16 sK[64][136];
  __shared__ __align__(16) u16 sVt[128][72];
  __shared__ __align__(16) u16 sP[48][72];
  __shared__ float sDen[48];

  int win = blockIdx.x, head = blockIdx.y, qf = blockIdx.z;
  if (wmaskp[win]) return;                    // dense windows handled by attn_dense
  int wi = win >> 3, wj = win & 7;
  int tid = threadIdx.x, lane = tid & 63, wave = tid >> 6;
  int quad = lane >> 4, tr = lane & 15;

  if (tid < 48) sDen[tid] = 0.f;

#pragma unroll
  for (int r = 0; r < 3; r++){
    int u = tid + 256 * r;
    int row = u >> 4, dg = u & 15;
    uint4 val = make_uint4(0,0,0,0);
    if (row < 45){
      int hh = wi*5 + row/9, ww = wj*9 + row%9;
      val = *(const uint4*)(qb + ((size_t)((qf*40 + hh)*72 + ww)) * 512 + head*128 + dg*8);
    }
    *(uint4*)(&sQ[row][dg * 8]) = val;
  }

  const int nkeys = 45;
  f32x4 acc[3][2];
#pragma unroll
  for (int a = 0; a < 3; a++)
#pragma unroll
    for (int b = 0; b < 2; b++){ acc[a][b][0]=0.f; acc[a][b][1]=0.f; acc[a][b][2]=0.f; acc[a][b][3]=0.f; }

  // stage K (coalesced) and V (transposed)
#pragma unroll
  for (int r = 0; r < 4; r++){
    int u = tid + 256 * r;
    int key = u >> 4, dg = u & 15;
    uint4 val = make_uint4(0,0,0,0);
    if (key < nkeys) val = *(const uint4*)(key_src_local(key, qf, wi, wj, head, kb) + dg * 8);
    *(uint4*)(&sK[key][dg * 8]) = val;
  }
#pragma unroll
  for (int r = 0; r < 4; r++){
    int u = tid + 256 * r;
    int key = u & 63, dg = u >> 6;
    uint4 val = make_uint4(0,0,0,0);
    if (key < nkeys) val = *(const uint4*)(key_src_local(key, qf, wi, wj, head, vb) + dg * 8);
    u32 vv[4] = {val.x, val.y, val.z, val.w};
#pragma unroll
    for (int q2 = 0; q2 < 4; q2++){
      sVt[dg*8 + q2*2][key]     = (u16)(vv[q2] & 0xffff);
      sVt[dg*8 + q2*2 + 1][key] = (u16)(vv[q2] >> 16);
    }
  }
  __syncthreads();

#pragma unroll
  for (int mt = 0; mt < 3; mt++){
    f32x4 sacc = {0.f, 0.f, 0.f, 0.f};
#pragma unroll
    for (int kt = 0; kt < 4; kt++){
      bf16x8 a = *(const bf16x8*)(&sQ[mt*16 + tr][kt*32 + quad*8]);
      bf16x8 b = *(const bf16x8*)(&sK[wave*16 + tr][kt*32 + quad*8]);
      sacc = __builtin_amdgcn_mfma_f32_16x16x32_bf16(a, b, sacc, 0, 0, 0);
    }
    int colg = wave * 16 + tr;
    float pr4[4];
#pragma unroll
    for (int r2 = 0; r2 < 4; r2++){
      float p = (colg < nkeys) ? __expf(sacc[r2] * SCALE) : 0.f;
      u16 pb2 = f2bf(p);
      sP[mt*16 + quad*4 + r2][wave*16 + tr] = pb2;
      pr4[r2] = bf2f(pb2);
    }
#pragma unroll
    for (int r2 = 0; r2 < 4; r2++){
      float ps = pr4[r2];
      ps += __shfl_xor(ps, 1, 64);
      ps += __shfl_xor(ps, 2, 64);
      ps += __shfl_xor(ps, 4, 64);
      ps += __shfl_xor(ps, 8, 64);
      if (tr == 0) atomicAdd(&sDen[mt*16 + quad*4 + r2], ps);
    }
  }
  __syncthreads();

#pragma unroll
  for (int mt = 0; mt < 3; mt++)
#pragma unroll
    for (int nt = 0; nt < 2; nt++)
#pragma unroll
      for (int kt = 0; kt < 2; kt++){
        bf16x8 a = *(const bf16x8*)(&sP[mt*16 + tr][kt*32 + quad*8]);
        bf16x8 b = *(const bf16x8*)(&sVt[wave*32 + nt*16 + tr][kt*32 + quad*8]);
        acc[mt][nt] = __builtin_amdgcn_mfma_f32_16x16x32_bf16(a, b, acc[mt][nt], 0, 0, 0);
      }
  __syncthreads();

#pragma unroll
  for (int mt = 0; mt < 3; mt++)
#pragma unroll
    for (int r2 = 0; r2 < 4; r2++){
      int row = mt*16 + quad*4 + r2;
      if (row < 45){
        float dinv = 1.0f / sDen[row];
        int hh = wi*5 + row/9, ww = wj*9 + row%9;
        size_t base = ((size_t)((qf*40 + hh)*72 + ww)) * 512 + head * 128;
#pragma unroll
        for (int nt = 0; nt < 2; nt++){
          int col = wave*32 + nt*16 + tr;
          yb[base + col] = f2bf(acc[mt][nt][r2] * dinv);
        }
      }
    }
}

extern "C" void kernel_launch(void* const* d_in, const int* in_sizes, int n_in,
                              void* d_out, int out_size, void* d_ws, size_t ws_size,
                              hipStream_t stream)
{
  const float* x     = (const float*)d_in[0];
  const float* masks = (const float*)d_in[1];
  const float* Wq = (const float*)d_in[2];  const float* bq = (const float*)d_in[3];
  const float* Wk = (const float*)d_in[4];  const float* bk = (const float*)d_in[5];
  const float* Wv = (const float*)d_in[6];  const float* bv = (const float*)d_in[7];
  const float* Wp = (const float*)d_in[8];  const float* bp = (const float*)d_in[9];
  const float* pw = (const float*)d_in[10]; const float* pb = (const float*)d_in[11];
  float* out = (float*)d_out;

  char* ws = (char*)d_ws;
  size_t off = 0;
  auto alloc = [&](size_t bytes) -> char* {
    char* p = ws + off; off += (bytes + 255) & ~(size_t)255; return p;
  };
  u16* wt    = (u16*)alloc((size_t)4 * 512 * 512 * 2);
  u16* xbf   = (u16*)alloc((size_t)NTOK * 512 * 2);
  u16* qbuf  = (u16*)alloc((size_t)NTOK * 512 * 2);
  u16* kbuf  = (u16*)alloc((size_t)NTOK * 512 * 2);
  u16* vbuf  = (u16*)alloc((size_t)NTOK * 512 * 2);
  u16* pxbuf = (u16*)alloc((size_t)1080 * 512 * 2);
  u16* pkbuf = (u16*)alloc((size_t)1080 * 512 * 2);
  u16* pvbuf = (u16*)alloc((size_t)1080 * 512 * 2);
  u16* ybuf  = (u16*)alloc((size_t)NTOK * 512 * 2);
  int* wmaskb = (int*)alloc(64 * 4);
  int* vib    = (int*)alloc(148 * 4);

  convert_x<<<dim3((NTOK*512/4 + 255)/256), 256, 0, stream>>>(x, xbf, NTOK*512/4);
  transpose_w<<<dim3(1024, 4), 256, 0, stream>>>(Wq, Wk, Wv, Wp, wt);
  gemm_bias<<<dim3(135, 4, 3), 256, 0, stream>>>(xbf, wt, bq, bk, bv, qbuf, kbuf, vbuf, nullptr, 0, 1, 2, NTOK);
  pool_conv<<<dim3(2160), 256, 0, stream>>>(x, pw, pb, pxbuf);
  gemm_bias<<<dim3(9, 4, 2), 256, 0, stream>>>(pxbuf, wt, bk, bv, bv, pkbuf, pvbuf, pvbuf, nullptr, 1, 2, 2, 1080);
  prep<<<dim3(1), 128, 0, stream>>>(masks, wmaskb, vib);
  attn_dense<<<dim3(64, 4), 512, 0, stream>>>(qbuf, kbuf, vbuf, pkbuf, pvbuf, wmaskb, vib, ybuf);
  attn_local<<<dim3(64, 4, 6), 256, 0, stream>>>(qbuf, kbuf, vbuf, wmaskb, ybuf);
  gemm_bias<<<dim3(135, 4, 1), 256, 0, stream>>>(ybuf, wt, bp, bp, bp, nullptr, nullptr, nullptr, out, 3, 3, 3, NTOK);
}